// Round 1
// baseline (1451.395 us; speedup 1.0000x reference)
//
#include <hip/hip_runtime.h>
#include <math.h>

// ---------------- dims ----------------
static constexpr int B_ = 16, S_ = 512, H_ = 128, G4_ = 512, IN_ = 140;
static constexpr int GD_ = 256, N_ = 128, E_ = 48, P_ = 512, R_ = 97;
static constexpr int BANK_ = 768, UC_ = 1536; // U cols

__device__ __forceinline__ float sigf(float x) { return 1.0f / (1.0f + expf(-x)); }

// ---------------- K1: transpose Wih (both dirs) ----------------
__global__ void transpose_w(const float* __restrict__ Wf, const float* __restrict__ Wb,
                            float* __restrict__ WfT, float* __restrict__ WbT) {
    int i = blockIdx.x * 256 + threadIdx.x;
    if (i < G4_ * IN_) {
        int j = i / IN_, k = i % IN_;
        WfT[k * G4_ + j] = Wf[i];
        WbT[k * G4_ + j] = Wb[i];
    }
}

// ---------------- K2: embedding + x @ Wih^T + b  (both dirs) ----------------
// grid 512 blocks x 512 threads; 16 rows per block; row = t*16+b
__global__ __launch_bounds__(512) void embed_xpre(
    const int* __restrict__ words, const int* __restrict__ etype, const int* __restrict__ eidm,
    const float* __restrict__ wt, const float* __restrict__ tt, const float* __restrict__ it,
    const float* __restrict__ WfT, const float* __restrict__ WbT,
    const float* __restrict__ bf, const float* __restrict__ bb,
    float* __restrict__ xf, float* __restrict__ xb) {
    __shared__ float xl[16][IN_];
    int tid = threadIdx.x;
    int r0 = blockIdx.x * 16;
    for (int r = 0; r < 16; ++r) {
        int rid = r0 + r, s = rid >> 4, b = rid & 15;
        if (tid < IN_) {
            int k = tid; float v;
            if (k < 100)      { int w  = words[b * S_ + s]; v = wt[w * 100 + k]; }
            else if (k < 120) { int ty = etype[b * S_ + s]; v = tt[ty * 20 + (k - 100)]; }
            else              { int id = eidm[b * S_ + s];  v = it[id * 20 + (k - 120)]; }
            xl[r][k] = v;
        }
    }
    __syncthreads();
    int j = tid;
    float accf[16], accb[16];
    float bfv = bf[j], bbv = bb[j];
#pragma unroll
    for (int r = 0; r < 16; ++r) { accf[r] = bfv; accb[r] = bbv; }
#pragma unroll 4
    for (int k = 0; k < IN_; ++k) {
        float wf = WfT[k * G4_ + j], wb = WbT[k * G4_ + j];
#pragma unroll
        for (int r = 0; r < 16; ++r) {
            float x = xl[r][k];
            accf[r] += x * wf;
            accb[r] += x * wb;
        }
    }
#pragma unroll
    for (int r = 0; r < 16; ++r) {
        int rid = r0 + r;
        xf[rid * G4_ + j] = accf[r];
        xb[rid * G4_ + j] = accb[r];
    }
}

// ---------------- K3: BiLSTM, one chain per block ----------------
// grid 32 (dir*16+b), 512 threads. Whh row j in regs; h broadcast via LDS.
__global__ __launch_bounds__(512) void lstm_kernel(
    const float* __restrict__ xf, const float* __restrict__ xb,
    const float* __restrict__ Whf, const float* __restrict__ Whb,
    float* __restrict__ hf, float* __restrict__ hb) {
    int bid = blockIdx.x;
    int dir = bid >> 4, b = bid & 15;
    const float* xpre = dir ? xb : xf;
    const float* Whh  = dir ? Whb : Whf;
    float* outp       = dir ? hb : hf;
    int j = threadIdx.x;
    float w[128];
#pragma unroll
    for (int k = 0; k < 128; k += 4) {
        float4 v = *reinterpret_cast<const float4*>(&Whh[j * 128 + k]);
        w[k] = v.x; w[k + 1] = v.y; w[k + 2] = v.z; w[k + 3] = v.w;
    }
    __shared__ float hsh[128];
    __shared__ float gsh[512];
    float c = 0.0f;
    if (j < 128) hsh[j] = 0.0f;
    __syncthreads();
    float xnext = xpre[((dir ? (S_ - 1) : 0) * B_ + b) * G4_ + j];
    for (int t = 0; t < S_; ++t) {
        int tcur = dir ? (S_ - 1 - t) : t;
        float g = xnext;
        if (t < S_ - 1) {
            int tn = dir ? (S_ - 2 - t) : (t + 1);
            xnext = xpre[(tn * B_ + b) * G4_ + j];
        }
        const float4* h4 = reinterpret_cast<const float4*>(hsh);
        float g0 = g, g1 = 0.f, g2 = 0.f, g3 = 0.f;
#pragma unroll
        for (int kk = 0; kk < 32; ++kk) {
            float4 hv = h4[kk];
            g0 += w[4 * kk + 0] * hv.x;
            g1 += w[4 * kk + 1] * hv.y;
            g2 += w[4 * kk + 2] * hv.z;
            g3 += w[4 * kk + 3] * hv.w;
        }
        gsh[j] = (g0 + g1) + (g2 + g3);
        __syncthreads();
        if (j < 128) {
            float gi = gsh[j], gfv = gsh[128 + j], gg = gsh[256 + j], go = gsh[384 + j];
            float si = sigf(gi), sf = sigf(gfv), so = sigf(go);
            c = sf * c + si * tanhf(gg);
            float h = so * tanhf(c);
            hsh[j] = h;
            outp[(tcur * B_ + b) * H_ + j] = h;
        }
        __syncthreads();
    }
}

// ---------------- K4: span means -> feat slice 0 ----------------
// grid 2048 (b*128+n), 256 threads (channel)
__global__ void span_mean(const float* __restrict__ hf, const float* __restrict__ hb,
                          const int* __restrict__ ginfo, const int* __restrict__ gnum,
                          const int* __restrict__ srclen, float* __restrict__ feat) {
    int bidx = blockIdx.x, b = bidx >> 7, n = bidx & 127;
    int c = threadIdx.x;
    int st = ginfo[(b * N_ + n) * 4 + 0];
    int en = ginfo[(b * N_ + n) * 4 + 1];
    int num = gnum[b], lb = srclen[b];
    float acc = 0.0f;
    for (int s = st; s < en; ++s) {
        if (s < lb) {
            acc += (c < H_) ? hf[(s * B_ + b) * H_ + c]
                            : hb[(s * B_ + b) * H_ + (c - H_)];
        }
    }
    int len = en - st; if (len < 1) len = 1;
    float v = acc / (float)len;
    if (n >= num) v = 0.0f;
    feat[(b * N_ + n) * BANK_ + c] = v;
}

// ---------------- K5: Anorm ----------------
__global__ void anorm_kernel(const int* __restrict__ adj, const int* __restrict__ gnum,
                             float* __restrict__ An) {
    int bidx = blockIdx.x, b = bidx >> 7, m = bidx & 127;
    int n = threadIdx.x;
    int num = gnum[b];
    float a = (adj[(b * N_ + m) * N_ + n] > 0 && m < num && n < num) ? 1.0f : 0.0f;
    float r = a;
#pragma unroll
    for (int off = 32; off > 0; off >>= 1) r += __shfl_down(r, off, 64);
    __shared__ float wsum[2];
    if ((n & 63) == 0) wsum[n >> 6] = r;
    __syncthreads();
    float total = wsum[0] + wsum[1];
    An[(b * N_ + m) * N_ + n] = a / fmaxf(total, 1.0f);
}

// ---------------- K6: M = Anorm @ X(slice) ----------------
// grid (16, 32): 4 m-rows per block; 256 threads (channel)
__global__ void gcn_agg(const float* __restrict__ An, const float* __restrict__ feat,
                        int slice, float* __restrict__ M) {
    int b = blockIdx.x, m0 = blockIdx.y * 4;
    int tid = threadIdx.x;
    __shared__ float ar[4][N_];
    for (int e = tid; e < 4 * N_; e += 256)
        ar[e >> 7][e & 127] = An[(b * N_ + m0 + (e >> 7)) * N_ + (e & 127)];
    __syncthreads();
    float acc[4] = {0.f, 0.f, 0.f, 0.f};
    int c = tid;
    for (int n = 0; n < N_; ++n) {
        float x = feat[(b * N_ + n) * BANK_ + slice * GD_ + c];
#pragma unroll
        for (int r = 0; r < 4; ++r) acc[r] += ar[r][n] * x;
    }
#pragma unroll
    for (int r = 0; r < 4; ++r) M[(b * N_ + m0 + r) * GD_ + c] = acc[r];
}

// ---------------- K7: h = relu(M @ W + bias) -> feat slice ----------------
__global__ void gcn_dense(const float* __restrict__ M, const float* __restrict__ W,
                          const float* __restrict__ bias, float* __restrict__ feat,
                          int outslice) {
    int b = blockIdx.x, m0 = blockIdx.y * 4;
    int tid = threadIdx.x;
    __shared__ float mr[4][GD_];
    for (int e = tid; e < 4 * GD_; e += 256)
        mr[e >> 8][e & 255] = M[(b * N_ + m0 + (e >> 8)) * GD_ + (e & 255)];
    __syncthreads();
    int c = tid;
    float bv = bias[c];
    float acc[4] = {bv, bv, bv, bv};
    for (int d = 0; d < GD_; ++d) {
        float wv = W[d * GD_ + c];
#pragma unroll
        for (int r = 0; r < 4; ++r) acc[r] += mr[r][d] * wv;
    }
#pragma unroll
    for (int r = 0; r < 4; ++r)
        feat[(b * N_ + m0 + r) * BANK_ + outslice * GD_ + c] = fmaxf(acc[r], 0.0f);
}

// ---------------- K8: entity bank ----------------
// grid 768 (b*48+e), 256 threads
__global__ void ebank_kernel(const int* __restrict__ ginfo, const int* __restrict__ gnum,
                             const float* __restrict__ feat, float* __restrict__ eb) {
    int bidx = blockIdx.x, b = bidx / E_, e = bidx % E_;
    int tid = threadIdx.x;
    __shared__ int fl[N_];
    int num = gnum[b];
    if (tid < N_) {
        int n = tid;
        int id = ginfo[(b * N_ + n) * 4 + 2];
        int ty = ginfo[(b * N_ + n) * 4 + 3];
        fl[n] = (ty == 2 && n < num) ? id : -1;
    }
    __syncthreads();
    float a0 = 0.f, a1 = 0.f, a2 = 0.f; int cnt = 0;
    for (int n = 0; n < N_; ++n) {
        if (fl[n] == e) {
            ++cnt;
            const float* fp = &feat[(b * N_ + n) * BANK_];
            a0 += fp[tid]; a1 += fp[256 + tid]; a2 += fp[512 + tid];
        }
    }
    float inv = 1.0f / (float)(cnt > 0 ? cnt : 1);
    float* o = &eb[(b * E_ + e) * BANK_];
    o[tid] = a0 * inv; o[256 + tid] = a1 * inv; o[512 + tid] = a2 * inv;
}

// ---------------- K9: D = dis_table @ pW1[1536:1556] + pb1 ----------------
__global__ void dmat_kernel(const float* __restrict__ dis, const float* __restrict__ pW1,
                            const float* __restrict__ pb1, float* __restrict__ Dm) {
    int d = blockIdx.x;
    int c = blockIdx.y * 256 + threadIdx.x;
    float acc = pb1[c];
    for (int q = 0; q < 20; ++q)
        acc += dis[d * 20 + q] * pW1[(2 * BANK_ + q) * UC_ + c];
    Dm[d * UC_ + c] = acc;
}

// ---------------- K10: U1/U2 = entity_bank @ pW1 halves ----------------
// C[768 x 3072], K=768. grid (12, 48), 256 thr, 64x64 tile, 4x4 per thread.
__global__ __launch_bounds__(256) void ugemm(const float* __restrict__ eb,
                                             const float* __restrict__ pW1,
                                             float* __restrict__ U1, float* __restrict__ U2) {
    int rt = blockIdx.x, ct = blockIdx.y;
    int tid = threadIdx.x;
    int half = (ct >= 24) ? 1 : 0;
    int jbase = (ct - half * 24) * 64;
    int wrow = half * BANK_;
    __shared__ float At[32][68];
    __shared__ float Bt[32][68];
    int rg = tid >> 4, cg = tid & 15;
    int r0 = rt * 64;
    float acc[4][4] = {};
    for (int kc = 0; kc < BANK_; kc += 32) {
#pragma unroll
        for (int i = 0; i < 8; ++i) {
            int e = tid + i * 256, r = e >> 5, k = e & 31;
            At[k][r] = eb[(r0 + r) * BANK_ + kc + k];
        }
#pragma unroll
        for (int i = 0; i < 8; ++i) {
            int e = tid + i * 256, k = e >> 6, cc = e & 63;
            Bt[k][cc] = pW1[(wrow + kc + k) * UC_ + jbase + cc];
        }
        __syncthreads();
#pragma unroll
        for (int k = 0; k < 32; ++k) {
            float4 a  = *reinterpret_cast<const float4*>(&At[k][rg * 4]);
            float4 bv = *reinterpret_cast<const float4*>(&Bt[k][cg * 4]);
            float ax[4] = {a.x, a.y, a.z, a.w};
            float bx[4] = {bv.x, bv.y, bv.z, bv.w};
#pragma unroll
            for (int r = 0; r < 4; ++r)
#pragma unroll
                for (int q = 0; q < 4; ++q) acc[r][q] += ax[r] * bx[q];
        }
        __syncthreads();
    }
    float* U = half ? U2 : U1;
#pragma unroll
    for (int r = 0; r < 4; ++r)
#pragma unroll
        for (int q = 0; q < 4; ++q)
            U[(r0 + rg * 4 + r) * UC_ + jbase + cg * 4 + q] = acc[r][q];
}

// ---------------- K11: scores = tanh(U1[h]+U2[t]+D[d]) @ pW2 + pb2 ----------------
// grid 256 (32 rows each), 256 threads; KC=96; T^T[k][r] stride 36, W[k][c] stride 100.
__global__ __launch_bounds__(256) void scores_kernel(
    const float* __restrict__ U1, const float* __restrict__ U2, const float* __restrict__ Dm,
    const float* __restrict__ pW2, const float* __restrict__ pb2,
    const int* __restrict__ pairs, const int* __restrict__ pdist, float* __restrict__ out) {
    int blk = blockIdx.x;
    int row0 = blk * 32;
    int b = row0 >> 9, p0 = row0 & 511;
    int tid = threadIdx.x;
    __shared__ float Tt[96 * 36];
    __shared__ float Wl[96 * 100];
    __shared__ int hidx[32], tidx[32], didx[32];
    if (tid < 32) {
        int p = p0 + tid;
        hidx[tid] = pairs[(b * P_ + p) * 2 + 0];
        tidx[tid] = pairs[(b * P_ + p) * 2 + 1];
        didx[tid] = pdist[b * P_ + p];
    }
    __syncthreads();
    int rg = tid / 25, cg = tid % 25;   // 8 x 25 = 200 active
    bool act = tid < 200;
    float acc[4][4] = {};
    for (int kc = 0; kc < UC_; kc += 96) {
        // stage pW2 chunk
        for (int k2 = tid; k2 < 96 * 128; k2 += 256) {
            int k = k2 >> 7, cc = k2 & 127;
            if (cc < 100) Wl[k * 100 + cc] = (cc < R_) ? pW2[(kc + k) * R_ + cc] : 0.0f;
        }
        // stage tanh(U1+U2+D) transposed
        for (int e = tid; e < 32 * 96; e += 256) {
            int r = e / 96, k = e % 96, gk = kc + k;
            float v = U1[(b * E_ + hidx[r]) * UC_ + gk]
                    + U2[(b * E_ + tidx[r]) * UC_ + gk]
                    + Dm[didx[r] * UC_ + gk];
            Tt[k * 36 + r] = tanhf(v);
        }
        __syncthreads();
        if (act) {
#pragma unroll 4
            for (int k = 0; k < 96; ++k) {
                float4 a  = *reinterpret_cast<const float4*>(&Tt[k * 36 + rg * 4]);
                float4 wv = *reinterpret_cast<const float4*>(&Wl[k * 100 + cg * 4]);
                float ax[4] = {a.x, a.y, a.z, a.w};
                float wx[4] = {wv.x, wv.y, wv.z, wv.w};
#pragma unroll
                for (int r = 0; r < 4; ++r)
#pragma unroll
                    for (int q = 0; q < 4; ++q) acc[r][q] += ax[r] * wx[q];
            }
        }
        __syncthreads();
    }
    if (act) {
#pragma unroll
        for (int r = 0; r < 4; ++r) {
            int prow = row0 + rg * 4 + r;
#pragma unroll
            for (int q = 0; q < 4; ++q) {
                int col = cg * 4 + q;
                if (col < R_) out[prow * R_ + col] = acc[r][q] + pb2[col];
            }
        }
    }
}

// ---------------- launcher ----------------
extern "C" void kernel_launch(void* const* d_in, const int* in_sizes, int n_in,
                              void* d_out, int out_size, void* d_ws, size_t ws_size,
                              hipStream_t stream) {
    const int*   words  = (const int*)d_in[0];
    const int*   etype  = (const int*)d_in[2];
    const int*   eidm   = (const int*)d_in[3];
    const int*   srclen = (const int*)d_in[4];
    const int*   adj    = (const int*)d_in[5];
    const int*   ginfo  = (const int*)d_in[6];
    const int*   gnum   = (const int*)d_in[7];
    const int*   pairs  = (const int*)d_in[8];
    const int*   pdist  = (const int*)d_in[9];
    const float* wt     = (const float*)d_in[10];
    const float* tt     = (const float*)d_in[11];
    const float* it     = (const float*)d_in[12];
    const float* Wihf   = (const float*)d_in[13];
    const float* Whhf   = (const float*)d_in[14];
    const float* bf     = (const float*)d_in[15];
    const float* Wihb   = (const float*)d_in[16];
    const float* Whhb   = (const float*)d_in[17];
    const float* bb     = (const float*)d_in[18];
    const float* W1     = (const float*)d_in[19];
    const float* b1     = (const float*)d_in[20];
    const float* W2     = (const float*)d_in[21];
    const float* b2     = (const float*)d_in[22];
    const float* dis    = (const float*)d_in[23];
    const float* pW1    = (const float*)d_in[24];
    const float* pb1    = (const float*)d_in[25];
    const float* pW2    = (const float*)d_in[26];
    const float* pb2    = (const float*)d_in[27];
    float* out = (float*)d_out;

    char* wsb = (char*)d_ws;
    size_t off = 0;
    auto carve = [&](size_t nf) {
        float* p = (float*)(wsb + off);
        off += ((nf * 4 + 255) / 256) * 256;
        return p;
    };
    float* WfT  = carve((size_t)IN_ * G4_);
    float* WbT  = carve((size_t)IN_ * G4_);
    float* xf   = carve((size_t)S_ * B_ * G4_);
    float* xb   = carve((size_t)S_ * B_ * G4_);
    float* hfb  = carve((size_t)S_ * B_ * H_);
    float* hbb  = carve((size_t)S_ * B_ * H_);
    float* feat = carve((size_t)B_ * N_ * BANK_);
    float* An   = carve((size_t)B_ * N_ * N_);
    float* M    = carve((size_t)B_ * N_ * GD_);
    float* eb   = carve((size_t)B_ * E_ * BANK_);
    float* U1   = carve((size_t)B_ * E_ * UC_);
    float* U2   = carve((size_t)B_ * E_ * UC_);
    float* Dm   = carve((size_t)20 * UC_);
    (void)ws_size; (void)in_sizes; (void)n_in; (void)out_size;

    transpose_w<<<(G4_ * IN_ + 255) / 256, 256, 0, stream>>>(Wihf, Wihb, WfT, WbT);
    embed_xpre<<<512, 512, 0, stream>>>(words, etype, eidm, wt, tt, it, WfT, WbT, bf, bb, xf, xb);
    lstm_kernel<<<32, 512, 0, stream>>>(xf, xb, Whhf, Whhb, hfb, hbb);
    span_mean<<<B_ * N_, 256, 0, stream>>>(hfb, hbb, ginfo, gnum, srclen, feat);
    anorm_kernel<<<B_ * N_, 128, 0, stream>>>(adj, gnum, An);
    gcn_agg<<<dim3(16, 32), 256, 0, stream>>>(An, feat, 0, M);
    gcn_dense<<<dim3(16, 32), 256, 0, stream>>>(M, W1, b1, feat, 1);
    gcn_agg<<<dim3(16, 32), 256, 0, stream>>>(An, feat, 1, M);
    gcn_dense<<<dim3(16, 32), 256, 0, stream>>>(M, W2, b2, feat, 2);
    ebank_kernel<<<B_ * E_, 256, 0, stream>>>(ginfo, gnum, feat, eb);
    dmat_kernel<<<dim3(20, 6), 256, 0, stream>>>(dis, pW1, pb1, Dm);
    ugemm<<<dim3(12, 48), 256, 0, stream>>>(eb, pW1, U1, U2);
    scores_kernel<<<256, 256, 0, stream>>>(U1, U2, Dm, pW2, pb2, pairs, pdist, out);
}

// Round 2
// 1333.796 us; speedup vs baseline: 1.0882x; 1.0882x over previous
//
#include <hip/hip_runtime.h>
#include <math.h>

// ---------------- dims ----------------
static constexpr int B_ = 16, S_ = 512, H_ = 128, G4_ = 512, IN_ = 140;
static constexpr int GD_ = 256, N_ = 128, E_ = 48, P_ = 512, R_ = 97;
static constexpr int BANK_ = 768, UC_ = 1536; // U cols

__device__ __forceinline__ float sigf(float x) { return 1.0f / (1.0f + expf(-x)); }

// ---------------- K1: transpose Wih (both dirs) ----------------
__global__ void transpose_w(const float* __restrict__ Wf, const float* __restrict__ Wb,
                            float* __restrict__ WfT, float* __restrict__ WbT) {
    int i = blockIdx.x * 256 + threadIdx.x;
    if (i < G4_ * IN_) {
        int j = i / IN_, k = i % IN_;
        WfT[k * G4_ + j] = Wf[i];
        WbT[k * G4_ + j] = Wb[i];
    }
}

// ---------------- K2: embedding + x @ Wih^T + b  (both dirs) ----------------
// grid 512 blocks x 512 threads; 16 rows per block; row = t*16+b
__global__ __launch_bounds__(512) void embed_xpre(
    const int* __restrict__ words, const int* __restrict__ etype, const int* __restrict__ eidm,
    const float* __restrict__ wt, const float* __restrict__ tt, const float* __restrict__ it,
    const float* __restrict__ WfT, const float* __restrict__ WbT,
    const float* __restrict__ bf, const float* __restrict__ bb,
    float* __restrict__ xf, float* __restrict__ xb) {
    __shared__ float xl[16][IN_];
    int tid = threadIdx.x;
    int r0 = blockIdx.x * 16;
    for (int r = 0; r < 16; ++r) {
        int rid = r0 + r, s = rid >> 4, b = rid & 15;
        if (tid < IN_) {
            int k = tid; float v;
            if (k < 100)      { int w  = words[b * S_ + s]; v = wt[w * 100 + k]; }
            else if (k < 120) { int ty = etype[b * S_ + s]; v = tt[ty * 20 + (k - 100)]; }
            else              { int id = eidm[b * S_ + s];  v = it[id * 20 + (k - 120)]; }
            xl[r][k] = v;
        }
    }
    __syncthreads();
    int j = tid;
    float accf[16], accb[16];
    float bfv = bf[j], bbv = bb[j];
#pragma unroll
    for (int r = 0; r < 16; ++r) { accf[r] = bfv; accb[r] = bbv; }
#pragma unroll 4
    for (int k = 0; k < IN_; ++k) {
        float wf = WfT[k * G4_ + j], wb = WbT[k * G4_ + j];
#pragma unroll
        for (int r = 0; r < 16; ++r) {
            float x = xl[r][k];
            accf[r] += x * wf;
            accb[r] += x * wb;
        }
    }
#pragma unroll
    for (int r = 0; r < 16; ++r) {
        int rid = r0 + r;
        xf[rid * G4_ + j] = accf[r];
        xb[rid * G4_ + j] = accb[r];
    }
}

// ---------------- K3: BiLSTM, one chain per block ----------------
// grid 32 (dir*16+b), 512 threads = 8 waves x (16 units x 4 K-slices).
// Thread (wave,j4,ks): partials of gates i,f,g,o of unit j=wave*16+j4 over
// h[32ks..32ks+32). Reduce over ks via shfl_xor; nonlinearity in-lane;
// ONE barrier per step; h double-buffered in LDS (1KB).
__global__ __launch_bounds__(512, 1) void lstm_kernel(
    const float* __restrict__ xf, const float* __restrict__ xb,
    const float* __restrict__ Whf, const float* __restrict__ Whb,
    float* __restrict__ hf, float* __restrict__ hb) {
    int bid = blockIdx.x;
    int dir = bid >> 4, b = bid & 15;
    const float* xpre = dir ? xb : xf;
    const float* Whh  = dir ? Whb : Whf;
    float* outp       = dir ? hb : hf;
    int tid  = threadIdx.x;
    int wave = tid >> 6;
    int lane = tid & 63;
    int j4   = lane & 15;
    int ks   = lane >> 4;          // 0..3
    int j    = wave * 16 + j4;     // hidden unit 0..127

    // per-thread weights: 4 gates x 32 K-slice = 128 VGPRs, static indexing
    float4 w4[4][8];
#pragma unroll
    for (int g = 0; g < 4; ++g)
#pragma unroll
        for (int q = 0; q < 8; ++q)
            w4[g][q] = *reinterpret_cast<const float4*>(
                &Whh[(j + 128 * g) * 128 + 32 * ks + 4 * q]);

    __shared__ float hsh[2][128];
    if (tid < 128) { hsh[0][tid] = 0.0f; hsh[1][tid] = 0.0f; }
    float c = 0.0f;

    int t0 = dir ? (S_ - 1) : 0;
    const float* xr0 = &xpre[(t0 * B_ + b) * G4_];
    float xi = xr0[j], xfv = xr0[j + 128], xg = xr0[j + 256], xo = xr0[j + 384];
    __syncthreads();

    for (int t = 0; t < S_; ++t) {
        int tcur = dir ? (S_ - 1 - t) : t;
        float cxi = xi, cxf = xfv, cxg = xg, cxo = xo;
        if (t < S_ - 1) {
            int tn = dir ? (S_ - 2 - t) : (t + 1);
            const float* xr = &xpre[(tn * B_ + b) * G4_];
            xi = xr[j]; xfv = xr[j + 128]; xg = xr[j + 256]; xo = xr[j + 384];
        }
        const float4* h4 = reinterpret_cast<const float4*>(&hsh[t & 1][32 * ks]);
        float ai = 0.f, af = 0.f, ag = 0.f, ao = 0.f;
#pragma unroll
        for (int q = 0; q < 8; ++q) {
            float4 hv = h4[q];
            ai += w4[0][q].x * hv.x + w4[0][q].y * hv.y + w4[0][q].z * hv.z + w4[0][q].w * hv.w;
            af += w4[1][q].x * hv.x + w4[1][q].y * hv.y + w4[1][q].z * hv.z + w4[1][q].w * hv.w;
            ag += w4[2][q].x * hv.x + w4[2][q].y * hv.y + w4[2][q].z * hv.z + w4[2][q].w * hv.w;
            ao += w4[3][q].x * hv.x + w4[3][q].y * hv.y + w4[3][q].z * hv.z + w4[3][q].w * hv.w;
        }
        // reduce across ks (lane bits 4,5)
        ai += __shfl_xor(ai, 16); ai += __shfl_xor(ai, 32);
        af += __shfl_xor(af, 16); af += __shfl_xor(af, 32);
        ag += __shfl_xor(ag, 16); ag += __shfl_xor(ag, 32);
        ao += __shfl_xor(ao, 16); ao += __shfl_xor(ao, 32);
        ai += cxi; af += cxf; ag += cxg; ao += cxo;
        float si = sigf(ai), sf = sigf(af), so = sigf(ao);
        c = sf * c + si * tanhf(ag);
        float h = so * tanhf(c);
        if (ks == 0) {
            hsh[1 - (t & 1)][j] = h;
            outp[(tcur * B_ + b) * H_ + j] = h;
        }
        __syncthreads();
    }
}

// ---------------- K4: span means -> feat slice 0 ----------------
// grid 2048 (b*128+n), 256 threads (channel)
__global__ void span_mean(const float* __restrict__ hf, const float* __restrict__ hb,
                          const int* __restrict__ ginfo, const int* __restrict__ gnum,
                          const int* __restrict__ srclen, float* __restrict__ feat) {
    int bidx = blockIdx.x, b = bidx >> 7, n = bidx & 127;
    int c = threadIdx.x;
    int st = ginfo[(b * N_ + n) * 4 + 0];
    int en = ginfo[(b * N_ + n) * 4 + 1];
    int num = gnum[b], lb = srclen[b];
    float acc = 0.0f;
    for (int s = st; s < en; ++s) {
        if (s < lb) {
            acc += (c < H_) ? hf[(s * B_ + b) * H_ + c]
                            : hb[(s * B_ + b) * H_ + (c - H_)];
        }
    }
    int len = en - st; if (len < 1) len = 1;
    float v = acc / (float)len;
    if (n >= num) v = 0.0f;
    feat[(b * N_ + n) * BANK_ + c] = v;
}

// ---------------- K5: Anorm ----------------
__global__ void anorm_kernel(const int* __restrict__ adj, const int* __restrict__ gnum,
                             float* __restrict__ An) {
    int bidx = blockIdx.x, b = bidx >> 7, m = bidx & 127;
    int n = threadIdx.x;
    int num = gnum[b];
    float a = (adj[(b * N_ + m) * N_ + n] > 0 && m < num && n < num) ? 1.0f : 0.0f;
    float r = a;
#pragma unroll
    for (int off = 32; off > 0; off >>= 1) r += __shfl_down(r, off, 64);
    __shared__ float wsum[2];
    if ((n & 63) == 0) wsum[n >> 6] = r;
    __syncthreads();
    float total = wsum[0] + wsum[1];
    An[(b * N_ + m) * N_ + n] = a / fmaxf(total, 1.0f);
}

// ---------------- K6: M = Anorm @ X(slice) ----------------
// grid (16, 32): 4 m-rows per block; 256 threads (channel)
__global__ void gcn_agg(const float* __restrict__ An, const float* __restrict__ feat,
                        int slice, float* __restrict__ M) {
    int b = blockIdx.x, m0 = blockIdx.y * 4;
    int tid = threadIdx.x;
    __shared__ float ar[4][N_];
    for (int e = tid; e < 4 * N_; e += 256)
        ar[e >> 7][e & 127] = An[(b * N_ + m0 + (e >> 7)) * N_ + (e & 127)];
    __syncthreads();
    float acc[4] = {0.f, 0.f, 0.f, 0.f};
    int c = tid;
    for (int n = 0; n < N_; ++n) {
        float x = feat[(b * N_ + n) * BANK_ + slice * GD_ + c];
#pragma unroll
        for (int r = 0; r < 4; ++r) acc[r] += ar[r][n] * x;
    }
#pragma unroll
    for (int r = 0; r < 4; ++r) M[(b * N_ + m0 + r) * GD_ + c] = acc[r];
}

// ---------------- K7: h = relu(M @ W + bias) -> feat slice ----------------
__global__ void gcn_dense(const float* __restrict__ M, const float* __restrict__ W,
                          const float* __restrict__ bias, float* __restrict__ feat,
                          int outslice) {
    int b = blockIdx.x, m0 = blockIdx.y * 4;
    int tid = threadIdx.x;
    __shared__ float mr[4][GD_];
    for (int e = tid; e < 4 * GD_; e += 256)
        mr[e >> 8][e & 255] = M[(b * N_ + m0 + (e >> 8)) * GD_ + (e & 255)];
    __syncthreads();
    int c = tid;
    float bv = bias[c];
    float acc[4] = {bv, bv, bv, bv};
    for (int d = 0; d < GD_; ++d) {
        float wv = W[d * GD_ + c];
#pragma unroll
        for (int r = 0; r < 4; ++r) acc[r] += mr[r][d] * wv;
    }
#pragma unroll
    for (int r = 0; r < 4; ++r)
        feat[(b * N_ + m0 + r) * BANK_ + outslice * GD_ + c] = fmaxf(acc[r], 0.0f);
}

// ---------------- K8: entity bank ----------------
// grid 768 (b*48+e), 256 threads
__global__ void ebank_kernel(const int* __restrict__ ginfo, const int* __restrict__ gnum,
                             const float* __restrict__ feat, float* __restrict__ eb) {
    int bidx = blockIdx.x, b = bidx / E_, e = bidx % E_;
    int tid = threadIdx.x;
    __shared__ int fl[N_];
    int num = gnum[b];
    if (tid < N_) {
        int n = tid;
        int id = ginfo[(b * N_ + n) * 4 + 2];
        int ty = ginfo[(b * N_ + n) * 4 + 3];
        fl[n] = (ty == 2 && n < num) ? id : -1;
    }
    __syncthreads();
    float a0 = 0.f, a1 = 0.f, a2 = 0.f; int cnt = 0;
    for (int n = 0; n < N_; ++n) {
        if (fl[n] == e) {
            ++cnt;
            const float* fp = &feat[(b * N_ + n) * BANK_];
            a0 += fp[tid]; a1 += fp[256 + tid]; a2 += fp[512 + tid];
        }
    }
    float inv = 1.0f / (float)(cnt > 0 ? cnt : 1);
    float* o = &eb[(b * E_ + e) * BANK_];
    o[tid] = a0 * inv; o[256 + tid] = a1 * inv; o[512 + tid] = a2 * inv;
}

// ---------------- K9: D = dis_table @ pW1[1536:1556] + pb1 ----------------
__global__ void dmat_kernel(const float* __restrict__ dis, const float* __restrict__ pW1,
                            const float* __restrict__ pb1, float* __restrict__ Dm) {
    int d = blockIdx.x;
    int c = blockIdx.y * 256 + threadIdx.x;
    float acc = pb1[c];
    for (int q = 0; q < 20; ++q)
        acc += dis[d * 20 + q] * pW1[(2 * BANK_ + q) * UC_ + c];
    Dm[d * UC_ + c] = acc;
}

// ---------------- K10: U1/U2 = entity_bank @ pW1 halves ----------------
// C[768 x 3072], K=768. grid (12, 48), 256 thr, 64x64 tile, 4x4 per thread.
__global__ __launch_bounds__(256) void ugemm(const float* __restrict__ eb,
                                             const float* __restrict__ pW1,
                                             float* __restrict__ U1, float* __restrict__ U2) {
    int rt = blockIdx.x, ct = blockIdx.y;
    int tid = threadIdx.x;
    int half = (ct >= 24) ? 1 : 0;
    int jbase = (ct - half * 24) * 64;
    int wrow = half * BANK_;
    __shared__ float At[32][68];
    __shared__ float Bt[32][68];
    int rg = tid >> 4, cg = tid & 15;
    int r0 = rt * 64;
    float acc[4][4] = {};
    for (int kc = 0; kc < BANK_; kc += 32) {
#pragma unroll
        for (int i = 0; i < 8; ++i) {
            int e = tid + i * 256, r = e >> 5, k = e & 31;
            At[k][r] = eb[(r0 + r) * BANK_ + kc + k];
        }
#pragma unroll
        for (int i = 0; i < 8; ++i) {
            int e = tid + i * 256, k = e >> 6, cc = e & 63;
            Bt[k][cc] = pW1[(wrow + kc + k) * UC_ + jbase + cc];
        }
        __syncthreads();
#pragma unroll
        for (int k = 0; k < 32; ++k) {
            float4 a  = *reinterpret_cast<const float4*>(&At[k][rg * 4]);
            float4 bv = *reinterpret_cast<const float4*>(&Bt[k][cg * 4]);
            float ax[4] = {a.x, a.y, a.z, a.w};
            float bx[4] = {bv.x, bv.y, bv.z, bv.w};
#pragma unroll
            for (int r = 0; r < 4; ++r)
#pragma unroll
                for (int q = 0; q < 4; ++q) acc[r][q] += ax[r] * bx[q];
        }
        __syncthreads();
    }
    float* U = half ? U2 : U1;
#pragma unroll
    for (int r = 0; r < 4; ++r)
#pragma unroll
        for (int q = 0; q < 4; ++q)
            U[(r0 + rg * 4 + r) * UC_ + jbase + cg * 4 + q] = acc[r][q];
}

// ---------------- K11: scores = tanh(U1[h]+U2[t]+D[d]) @ pW2 + pb2 ----------------
// grid 256 (32 rows each), 256 threads; KC=96; T^T[k][r] stride 36, W[k][c] stride 100.
__global__ __launch_bounds__(256) void scores_kernel(
    const float* __restrict__ U1, const float* __restrict__ U2, const float* __restrict__ Dm,
    const float* __restrict__ pW2, const float* __restrict__ pb2,
    const int* __restrict__ pairs, const int* __restrict__ pdist, float* __restrict__ out) {
    int blk = blockIdx.x;
    int row0 = blk * 32;
    int b = row0 >> 9, p0 = row0 & 511;
    int tid = threadIdx.x;
    __shared__ float Tt[96 * 36];
    __shared__ float Wl[96 * 100];
    __shared__ int hidx[32], tidx[32], didx[32];
    if (tid < 32) {
        int p = p0 + tid;
        hidx[tid] = pairs[(b * P_ + p) * 2 + 0];
        tidx[tid] = pairs[(b * P_ + p) * 2 + 1];
        didx[tid] = pdist[b * P_ + p];
    }
    __syncthreads();
    int rg = tid / 25, cg = tid % 25;   // 8 x 25 = 200 active
    bool act = tid < 200;
    float acc[4][4] = {};
    for (int kc = 0; kc < UC_; kc += 96) {
        // stage pW2 chunk
        for (int k2 = tid; k2 < 96 * 128; k2 += 256) {
            int k = k2 >> 7, cc = k2 & 127;
            if (cc < 100) Wl[k * 100 + cc] = (cc < R_) ? pW2[(kc + k) * R_ + cc] : 0.0f;
        }
        // stage tanh(U1+U2+D) transposed
        for (int e = tid; e < 32 * 96; e += 256) {
            int r = e / 96, k = e % 96, gk = kc + k;
            float v = U1[(b * E_ + hidx[r]) * UC_ + gk]
                    + U2[(b * E_ + tidx[r]) * UC_ + gk]
                    + Dm[didx[r] * UC_ + gk];
            Tt[k * 36 + r] = tanhf(v);
        }
        __syncthreads();
        if (act) {
#pragma unroll 4
            for (int k = 0; k < 96; ++k) {
                float4 a  = *reinterpret_cast<const float4*>(&Tt[k * 36 + rg * 4]);
                float4 wv = *reinterpret_cast<const float4*>(&Wl[k * 100 + cg * 4]);
                float ax[4] = {a.x, a.y, a.z, a.w};
                float wx[4] = {wv.x, wv.y, wv.z, wv.w};
#pragma unroll
                for (int r = 0; r < 4; ++r)
#pragma unroll
                    for (int q = 0; q < 4; ++q) acc[r][q] += ax[r] * wx[q];
            }
        }
        __syncthreads();
    }
    if (act) {
#pragma unroll
        for (int r = 0; r < 4; ++r) {
            int prow = row0 + rg * 4 + r;
#pragma unroll
            for (int q = 0; q < 4; ++q) {
                int col = cg * 4 + q;
                if (col < R_) out[prow * R_ + col] = acc[r][q] + pb2[col];
            }
        }
    }
}

// ---------------- launcher ----------------
extern "C" void kernel_launch(void* const* d_in, const int* in_sizes, int n_in,
                              void* d_out, int out_size, void* d_ws, size_t ws_size,
                              hipStream_t stream) {
    const int*   words  = (const int*)d_in[0];
    const int*   etype  = (const int*)d_in[2];
    const int*   eidm   = (const int*)d_in[3];
    const int*   srclen = (const int*)d_in[4];
    const int*   adj    = (const int*)d_in[5];
    const int*   ginfo  = (const int*)d_in[6];
    const int*   gnum   = (const int*)d_in[7];
    const int*   pairs  = (const int*)d_in[8];
    const int*   pdist  = (const int*)d_in[9];
    const float* wt     = (const float*)d_in[10];
    const float* tt     = (const float*)d_in[11];
    const float* it     = (const float*)d_in[12];
    const float* Wihf   = (const float*)d_in[13];
    const float* Whhf   = (const float*)d_in[14];
    const float* bf     = (const float*)d_in[15];
    const float* Wihb   = (const float*)d_in[16];
    const float* Whhb   = (const float*)d_in[17];
    const float* bb     = (const float*)d_in[18];
    const float* W1     = (const float*)d_in[19];
    const float* b1     = (const float*)d_in[20];
    const float* W2     = (const float*)d_in[21];
    const float* b2     = (const float*)d_in[22];
    const float* dis    = (const float*)d_in[23];
    const float* pW1    = (const float*)d_in[24];
    const float* pb1    = (const float*)d_in[25];
    const float* pW2    = (const float*)d_in[26];
    const float* pb2    = (const float*)d_in[27];
    float* out = (float*)d_out;

    char* wsb = (char*)d_ws;
    size_t off = 0;
    auto carve = [&](size_t nf) {
        float* p = (float*)(wsb + off);
        off += ((nf * 4 + 255) / 256) * 256;
        return p;
    };
    float* WfT  = carve((size_t)IN_ * G4_);
    float* WbT  = carve((size_t)IN_ * G4_);
    float* xf   = carve((size_t)S_ * B_ * G4_);
    float* xb   = carve((size_t)S_ * B_ * G4_);
    float* hfb  = carve((size_t)S_ * B_ * H_);
    float* hbb  = carve((size_t)S_ * B_ * H_);
    float* feat = carve((size_t)B_ * N_ * BANK_);
    float* An   = carve((size_t)B_ * N_ * N_);
    float* M    = carve((size_t)B_ * N_ * GD_);
    float* eb   = carve((size_t)B_ * E_ * BANK_);
    float* U1   = carve((size_t)B_ * E_ * UC_);
    float* U2   = carve((size_t)B_ * E_ * UC_);
    float* Dm   = carve((size_t)20 * UC_);
    (void)ws_size; (void)in_sizes; (void)n_in; (void)out_size;

    transpose_w<<<(G4_ * IN_ + 255) / 256, 256, 0, stream>>>(Wihf, Wihb, WfT, WbT);
    embed_xpre<<<512, 512, 0, stream>>>(words, etype, eidm, wt, tt, it, WfT, WbT, bf, bb, xf, xb);
    lstm_kernel<<<32, 512, 0, stream>>>(xf, xb, Whhf, Whhb, hfb, hbb);
    span_mean<<<B_ * N_, 256, 0, stream>>>(hfb, hbb, ginfo, gnum, srclen, feat);
    anorm_kernel<<<B_ * N_, 128, 0, stream>>>(adj, gnum, An);
    gcn_agg<<<dim3(16, 32), 256, 0, stream>>>(An, feat, 0, M);
    gcn_dense<<<dim3(16, 32), 256, 0, stream>>>(M, W1, b1, feat, 1);
    gcn_agg<<<dim3(16, 32), 256, 0, stream>>>(An, feat, 1, M);
    gcn_dense<<<dim3(16, 32), 256, 0, stream>>>(M, W2, b2, feat, 2);
    ebank_kernel<<<B_ * E_, 256, 0, stream>>>(ginfo, gnum, feat, eb);
    dmat_kernel<<<dim3(20, 6), 256, 0, stream>>>(dis, pW1, pb1, Dm);
    ugemm<<<dim3(12, 48), 256, 0, stream>>>(eb, pW1, U1, U2);
    scores_kernel<<<256, 256, 0, stream>>>(U1, U2, Dm, pW2, pb2, pairs, pdist, out);
}

// Round 4
// 1100.643 us; speedup vs baseline: 1.3187x; 1.2118x over previous
//
#include <hip/hip_runtime.h>
#include <math.h>

// ---------------- dims ----------------
static constexpr int B_ = 16, S_ = 512, H_ = 128, G4_ = 512, IN_ = 140;
static constexpr int GD_ = 256, N_ = 128, E_ = 48, P_ = 512, R_ = 97;
static constexpr int BANK_ = 768, UC_ = 1536; // U cols

__device__ __forceinline__ float fsig(float x) {
    return __builtin_amdgcn_rcpf(1.0f + __expf(-x));
}
__device__ __forceinline__ float ftanh(float x) {
    float e = __expf(2.0f * fminf(x, 15.0f));
    return (e - 1.0f) * __builtin_amdgcn_rcpf(e + 1.0f);
}

// ---------------- K0: fused prep: transpose Wih | Anorm | Dm ----------------
// blocks [0,280): transpose; [280,1304): Anorm (2 rows each); [1304,1424): Dm
__global__ __launch_bounds__(256) void misc_prep(
    const float* __restrict__ Wf, const float* __restrict__ Wb,
    float* __restrict__ WfT, float* __restrict__ WbT,
    const int* __restrict__ adj, const int* __restrict__ gnum, float* __restrict__ An,
    const float* __restrict__ dis, const float* __restrict__ pW1,
    const float* __restrict__ pb1, float* __restrict__ Dm) {
    int bid = blockIdx.x, tid = threadIdx.x;
    if (bid < 280) {
        int i = bid * 256 + tid;
        if (i < G4_ * IN_) {
            int jj = i / IN_, k = i - jj * IN_;
            WfT[k * G4_ + jj] = Wf[i];
            WbT[k * G4_ + jj] = Wb[i];
        }
    } else if (bid < 1304) {
        int rr = (bid - 280) * 2 + (tid >> 7);
        int b = rr >> 7, m = rr & 127, n = tid & 127;
        int num = gnum[b];
        float a = (adj[(b * N_ + m) * N_ + n] > 0 && m < num && n < num) ? 1.0f : 0.0f;
        float r = a;
#pragma unroll
        for (int off = 32; off > 0; off >>= 1) r += __shfl_down(r, off, 64);
        __shared__ float ws4[4];
        if ((tid & 63) == 0) ws4[tid >> 6] = r;
        __syncthreads();
        int w0 = (tid >> 7) * 2;
        float total = ws4[w0] + ws4[w0 + 1];
        An[(b * N_ + m) * N_ + n] = a / fmaxf(total, 1.0f);
    } else {
        int e = bid - 1304;
        int d = e / 6, cch = e - d * 6;
        int ci = cch * 256 + tid;
        float acc = pb1[ci];
#pragma unroll 4
        for (int q = 0; q < 20; ++q) acc += dis[d * 20 + q] * pW1[(2 * BANK_ + q) * UC_ + ci];
        Dm[d * UC_ + ci] = acc;
    }
}

// ---------------- K2: embedding + x @ Wih^T + b  (both dirs) ----------------
// grid 512 blocks x 512 threads; 16 rows per block; row = t*16+b
// xl is k-major [140][20] (pad 20 keeps float4 rows 16B-aligned, spreads banks)
__global__ __launch_bounds__(512) void embed_xpre(
    const int* __restrict__ words, const int* __restrict__ etype, const int* __restrict__ eidm,
    const float* __restrict__ wt, const float* __restrict__ tt, const float* __restrict__ it,
    const float* __restrict__ WfT, const float* __restrict__ WbT,
    const float* __restrict__ bf, const float* __restrict__ bb,
    float* __restrict__ xf, float* __restrict__ xb) {
    __shared__ float xl[IN_][20];
    int tid = threadIdx.x;
    int r0 = blockIdx.x * 16;
    for (int e = tid; e < 16 * IN_; e += 512) {
        int r = e / IN_, k = e - r * IN_;
        int rid = r0 + r, s = rid >> 4, b = rid & 15;
        float v;
        if (k < 100)      v = wt[words[b * S_ + s] * 100 + k];
        else if (k < 120) v = tt[etype[b * S_ + s] * 20 + (k - 100)];
        else              v = it[eidm[b * S_ + s] * 20 + (k - 120)];
        xl[k][r] = v;
    }
    __syncthreads();
    int j = tid;
    float accf[16], accb[16];
    float bfv = bf[j], bbv = bb[j];
#pragma unroll
    for (int r = 0; r < 16; ++r) { accf[r] = bfv; accb[r] = bbv; }
#pragma unroll 2
    for (int k = 0; k < IN_; ++k) {
        float wf = WfT[k * G4_ + j], wb = WbT[k * G4_ + j];
        float4 x0 = *reinterpret_cast<const float4*>(&xl[k][0]);
        float4 x1 = *reinterpret_cast<const float4*>(&xl[k][4]);
        float4 x2 = *reinterpret_cast<const float4*>(&xl[k][8]);
        float4 x3 = *reinterpret_cast<const float4*>(&xl[k][12]);
        float xr[16] = {x0.x, x0.y, x0.z, x0.w, x1.x, x1.y, x1.z, x1.w,
                        x2.x, x2.y, x2.z, x2.w, x3.x, x3.y, x3.z, x3.w};
#pragma unroll
        for (int r = 0; r < 16; ++r) {
            accf[r] += xr[r] * wf;
            accb[r] += xr[r] * wb;
        }
    }
#pragma unroll
    for (int r = 0; r < 16; ++r) {
        int rid = r0 + r;
        xf[rid * G4_ + j] = accf[r];
        xb[rid * G4_ + j] = accb[r];
    }
}

// ---------------- K3: BiLSTM, one chain per block ----------------
// grid 32 (dir*16+b), 512 threads = 8 waves x (16 units x 4 K-slices).
// NOTE: Whh / output pointers deliberately NOT __restrict__ — in-loop global
// stores may alias the weights, which forbids the compiler from sinking the
// pre-loop weight loads into the loop (keeps 128 weight floats in VGPRs).
__global__ __launch_bounds__(512, 2) void lstm_kernel(
    const float* __restrict__ xf, const float* __restrict__ xb,
    const float* Whf, const float* Whb,
    float* hfo, float* hbo) {
    int bid = blockIdx.x;
    int dir = bid >> 4, b = bid & 15;
    const float* xpre = dir ? xb : xf;
    const float* Whh  = dir ? Whb : Whf;
    float* outp       = dir ? hbo : hfo;
    int tid  = threadIdx.x;
    int wave = tid >> 6;
    int lane = tid & 63;
    int j4   = lane & 15;
    int ks   = lane >> 4;          // 0..3
    int j    = wave * 16 + j4;     // hidden unit 0..127

    // per-thread weights: 4 gates x 32 K-slice = 128 VGPRs, static indexing
    float4 w4[4][8];
#pragma unroll
    for (int g = 0; g < 4; ++g)
#pragma unroll
        for (int q = 0; q < 8; ++q)
            w4[g][q] = *reinterpret_cast<const float4*>(
                &Whh[(j + 128 * g) * 128 + 32 * ks + 4 * q]);

    // h double-buffered; slice ks stored at row ks (stride 36 floats -> the
    // 4 slices start at banks 0,4,8,12: conflict-free b128 reads)
    __shared__ float hsh[2][4 * 36];
    if (tid < 128) {
        hsh[0][(tid >> 5) * 36 + (tid & 31)] = 0.0f;
        hsh[1][(tid >> 5) * 36 + (tid & 31)] = 0.0f;
    }
    float c = 0.0f;

    int t0 = dir ? (S_ - 1) : 0;
    const float* xr0 = &xpre[(t0 * B_ + b) * G4_];
    float xi = xr0[j], xfv = xr0[j + 128], xg = xr0[j + 256], xo = xr0[j + 384];
    __syncthreads();

    for (int t = 0; t < S_; ++t) {
        int tcur = dir ? (S_ - 1 - t) : t;
        float cxi = xi, cxf = xfv, cxg = xg, cxo = xo;
        if (t < S_ - 1) {
            int tn = dir ? (S_ - 2 - t) : (t + 1);
            const float* xr = &xpre[(tn * B_ + b) * G4_];
            xi = xr[j]; xfv = xr[j + 128]; xg = xr[j + 256]; xo = xr[j + 384];
        }
        const float* hrow = &hsh[t & 1][ks * 36];
        float ai = 0.f, af = 0.f, ag = 0.f, ao = 0.f;
#pragma unroll
        for (int q = 0; q < 8; ++q) {
            float4 hv = *reinterpret_cast<const float4*>(&hrow[4 * q]);
            ai += w4[0][q].x * hv.x + w4[0][q].y * hv.y + w4[0][q].z * hv.z + w4[0][q].w * hv.w;
            af += w4[1][q].x * hv.x + w4[1][q].y * hv.y + w4[1][q].z * hv.z + w4[1][q].w * hv.w;
            ag += w4[2][q].x * hv.x + w4[2][q].y * hv.y + w4[2][q].z * hv.z + w4[2][q].w * hv.w;
            ao += w4[3][q].x * hv.x + w4[3][q].y * hv.y + w4[3][q].z * hv.z + w4[3][q].w * hv.w;
        }
        // reduce across ks (lane bits 4,5)
        ai += __shfl_xor(ai, 16); ai += __shfl_xor(ai, 32);
        af += __shfl_xor(af, 16); af += __shfl_xor(af, 32);
        ag += __shfl_xor(ag, 16); ag += __shfl_xor(ag, 32);
        ao += __shfl_xor(ao, 16); ao += __shfl_xor(ao, 32);
        ai += cxi; af += cxf; ag += cxg; ao += cxo;
        float si = fsig(ai), sf = fsig(af), so = fsig(ao);
        c = sf * c + si * ftanh(ag);
        float h = so * ftanh(c);
        if (ks == 0) {
            hsh[1 - (t & 1)][(j >> 5) * 36 + (j & 31)] = h;
            outp[(tcur * B_ + b) * H_ + j] = h;
        }
        __syncthreads();
    }
}

// ---------------- K4: span means -> feat slice 0 ----------------
// grid 2048 (b*128+n), 256 threads (channel)
__global__ void span_mean(const float* __restrict__ hf, const float* __restrict__ hb,
                          const int* __restrict__ ginfo, const int* __restrict__ gnum,
                          const int* __restrict__ srclen, float* __restrict__ feat) {
    int bidx = blockIdx.x, b = bidx >> 7, n = bidx & 127;
    int c = threadIdx.x;
    int st = ginfo[(b * N_ + n) * 4 + 0];
    int en = ginfo[(b * N_ + n) * 4 + 1];
    int num = gnum[b], lb = srclen[b];
    float acc = 0.0f;
    for (int s = st; s < en; ++s) {
        if (s < lb) {
            acc += (c < H_) ? hf[(s * B_ + b) * H_ + c]
                            : hb[(s * B_ + b) * H_ + (c - H_)];
        }
    }
    int len = en - st; if (len < 1) len = 1;
    float v = acc / (float)len;
    if (n >= num) v = 0.0f;
    feat[(b * N_ + n) * BANK_ + c] = v;
}

// ---------------- K6: M = Anorm @ X(slice) ----------------
// grid (16, 32): 4 m-rows per block; 256 threads (channel)
__global__ void gcn_agg(const float* __restrict__ An, const float* __restrict__ feat,
                        int slice, float* __restrict__ M) {
    int b = blockIdx.x, m0 = blockIdx.y * 4;
    int tid = threadIdx.x;
    __shared__ float ar[4][N_];
    for (int e = tid; e < 4 * N_; e += 256)
        ar[e >> 7][e & 127] = An[(b * N_ + m0 + (e >> 7)) * N_ + (e & 127)];
    __syncthreads();
    float acc[4] = {0.f, 0.f, 0.f, 0.f};
    int c = tid;
    const float* fbase = &feat[(size_t)b * N_ * BANK_ + slice * GD_ + c];
    for (int n = 0; n < N_; n += 4) {
        float x0 = fbase[(size_t)(n + 0) * BANK_];
        float x1 = fbase[(size_t)(n + 1) * BANK_];
        float x2 = fbase[(size_t)(n + 2) * BANK_];
        float x3 = fbase[(size_t)(n + 3) * BANK_];
#pragma unroll
        for (int r = 0; r < 4; ++r) {
            float4 a = *reinterpret_cast<const float4*>(&ar[r][n]);
            acc[r] += a.x * x0 + a.y * x1 + a.z * x2 + a.w * x3;
        }
    }
#pragma unroll
    for (int r = 0; r < 4; ++r) M[(b * N_ + m0 + r) * GD_ + c] = acc[r];
}

// ---------------- K7: h = relu(M @ W + bias) -> feat slice ----------------
__global__ void gcn_dense(const float* __restrict__ M, const float* __restrict__ W,
                          const float* __restrict__ bias, float* __restrict__ feat,
                          int outslice) {
    int b = blockIdx.x, m0 = blockIdx.y * 4;
    int tid = threadIdx.x;
    __shared__ float mr[4][GD_];
    for (int e = tid; e < 4 * GD_; e += 256)
        mr[e >> 8][e & 255] = M[(b * N_ + m0 + (e >> 8)) * GD_ + (e & 255)];
    __syncthreads();
    int c = tid;
    float bv = bias[c];
    float acc[4] = {bv, bv, bv, bv};
    for (int d = 0; d < GD_; d += 4) {
        float w0 = W[(d + 0) * GD_ + c];
        float w1 = W[(d + 1) * GD_ + c];
        float w2 = W[(d + 2) * GD_ + c];
        float w3 = W[(d + 3) * GD_ + c];
#pragma unroll
        for (int r = 0; r < 4; ++r) {
            float4 m = *reinterpret_cast<const float4*>(&mr[r][d]);
            acc[r] += m.x * w0 + m.y * w1 + m.z * w2 + m.w * w3;
        }
    }
#pragma unroll
    for (int r = 0; r < 4; ++r)
        feat[(b * N_ + m0 + r) * BANK_ + outslice * GD_ + c] = fmaxf(acc[r], 0.0f);
}

// ---------------- K8: entity bank ----------------
// grid 768 (b*48+e), 256 threads
__global__ void ebank_kernel(const int* __restrict__ ginfo, const int* __restrict__ gnum,
                             const float* __restrict__ feat, float* __restrict__ eb) {
    int bidx = blockIdx.x, b = bidx / E_, e = bidx % E_;
    int tid = threadIdx.x;
    __shared__ int fl[N_];
    int num = gnum[b];
    if (tid < N_) {
        int n = tid;
        int id = ginfo[(b * N_ + n) * 4 + 2];
        int ty = ginfo[(b * N_ + n) * 4 + 3];
        fl[n] = (ty == 2 && n < num) ? id : -1;
    }
    __syncthreads();
    float a0 = 0.f, a1 = 0.f, a2 = 0.f; int cnt = 0;
    for (int n = 0; n < N_; ++n) {
        if (fl[n] == e) {
            ++cnt;
            const float* fp = &feat[(b * N_ + n) * BANK_];
            a0 += fp[tid]; a1 += fp[256 + tid]; a2 += fp[512 + tid];
        }
    }
    float inv = 1.0f / (float)(cnt > 0 ? cnt : 1);
    float* o = &eb[(b * E_ + e) * BANK_];
    o[tid] = a0 * inv; o[256 + tid] = a1 * inv; o[512 + tid] = a2 * inv;
}

// ---------------- K10: U1/U2 = entity_bank @ pW1 halves ----------------
// C[768 x 3072], K=768. grid (12, 48), 256 thr, 64x64 tile, 4x4 per thread.
__global__ __launch_bounds__(256) void ugemm(const float* __restrict__ eb,
                                             const float* __restrict__ pW1,
                                             float* __restrict__ U1, float* __restrict__ U2) {
    int rt = blockIdx.x, ct = blockIdx.y;
    int tid = threadIdx.x;
    int half = (ct >= 24) ? 1 : 0;
    int jbase = (ct - half * 24) * 64;
    int wrow = half * BANK_;
    __shared__ float At[32][68];
    __shared__ float Bt[32][68];
    int rg = tid >> 4, cg = tid & 15;
    int r0 = rt * 64;
    float acc[4][4] = {};
    for (int kc = 0; kc < BANK_; kc += 32) {
#pragma unroll
        for (int i = 0; i < 8; ++i) {
            int e = tid + i * 256, r = e >> 5, k = e & 31;
            At[k][r] = eb[(r0 + r) * BANK_ + kc + k];
        }
#pragma unroll
        for (int i = 0; i < 8; ++i) {
            int e = tid + i * 256, k = e >> 6, cc = e & 63;
            Bt[k][cc] = pW1[(wrow + kc + k) * UC_ + jbase + cc];
        }
        __syncthreads();
#pragma unroll
        for (int k = 0; k < 32; ++k) {
            float4 a  = *reinterpret_cast<const float4*>(&At[k][rg * 4]);
            float4 bv = *reinterpret_cast<const float4*>(&Bt[k][cg * 4]);
            float ax[4] = {a.x, a.y, a.z, a.w};
            float bx[4] = {bv.x, bv.y, bv.z, bv.w};
#pragma unroll
            for (int r = 0; r < 4; ++r)
#pragma unroll
                for (int q = 0; q < 4; ++q) acc[r][q] += ax[r] * bx[q];
        }
        __syncthreads();
    }
    float* U = half ? U2 : U1;
#pragma unroll
    for (int r = 0; r < 4; ++r)
#pragma unroll
        for (int q = 0; q < 4; ++q)
            U[(r0 + rg * 4 + r) * UC_ + jbase + cg * 4 + q] = acc[r][q];
}

// ---------------- K11: scores = tanh(U1[h]+U2[t]+D[d]) @ pW2 + pb2 ----------------
// grid 256 (32 rows each), 256 threads; KC=96; T^T[k][r] stride 36, W[k][c] stride 100.
__global__ __launch_bounds__(256) void scores_kernel(
    const float* __restrict__ U1, const float* __restrict__ U2, const float* __restrict__ Dm,
    const float* __restrict__ pW2, const float* __restrict__ pb2,
    const int* __restrict__ pairs, const int* __restrict__ pdist, float* __restrict__ out) {
    int blk = blockIdx.x;
    int row0 = blk * 32;
    int b = row0 >> 9, p0 = row0 & 511;
    int tid = threadIdx.x;
    __shared__ float Tt[96 * 36];
    __shared__ float Wl[96 * 100];
    __shared__ int hidx[32], tidx[32], didx[32];
    if (tid < 32) {
        int p = p0 + tid;
        hidx[tid] = pairs[(b * P_ + p) * 2 + 0];
        tidx[tid] = pairs[(b * P_ + p) * 2 + 1];
        didx[tid] = pdist[b * P_ + p];
    }
    __syncthreads();
    int rg = tid / 25, cg = tid % 25;   // 8 x 25 = 200 active
    bool act = tid < 200;
    float acc[4][4] = {};
    for (int kc = 0; kc < UC_; kc += 96) {
        // stage pW2 chunk
        for (int k2 = tid; k2 < 96 * 128; k2 += 256) {
            int k = k2 >> 7, cc = k2 & 127;
            if (cc < 100) Wl[k * 100 + cc] = (cc < R_) ? pW2[(kc + k) * R_ + cc] : 0.0f;
        }
        // stage tanh(U1+U2+D) transposed
        for (int e = tid; e < 32 * 96; e += 256) {
            int r = e / 96, k = e % 96, gk = kc + k;
            float v = U1[(b * E_ + hidx[r]) * UC_ + gk]
                    + U2[(b * E_ + tidx[r]) * UC_ + gk]
                    + Dm[didx[r] * UC_ + gk];
            Tt[k * 36 + r] = ftanh(v);
        }
        __syncthreads();
        if (act) {
#pragma unroll 4
            for (int k = 0; k < 96; ++k) {
                float4 a  = *reinterpret_cast<const float4*>(&Tt[k * 36 + rg * 4]);
                float4 wv = *reinterpret_cast<const float4*>(&Wl[k * 100 + cg * 4]);
                float ax[4] = {a.x, a.y, a.z, a.w};
                float wx[4] = {wv.x, wv.y, wv.z, wv.w};
#pragma unroll
                for (int r = 0; r < 4; ++r)
#pragma unroll
                    for (int q = 0; q < 4; ++q) acc[r][q] += ax[r] * wx[q];
            }
        }
        __syncthreads();
    }
    if (act) {
#pragma unroll
        for (int r = 0; r < 4; ++r) {
            int prow = row0 + rg * 4 + r;
#pragma unroll
            for (int q = 0; q < 4; ++q) {
                int col = cg * 4 + q;
                if (col < R_) out[prow * R_ + col] = acc[r][q] + pb2[col];
            }
        }
    }
}

// ---------------- launcher ----------------
extern "C" void kernel_launch(void* const* d_in, const int* in_sizes, int n_in,
                              void* d_out, int out_size, void* d_ws, size_t ws_size,
                              hipStream_t stream) {
    const int*   words  = (const int*)d_in[0];
    const int*   etype  = (const int*)d_in[2];
    const int*   eidm   = (const int*)d_in[3];
    const int*   srclen = (const int*)d_in[4];
    const int*   adj    = (const int*)d_in[5];
    const int*   ginfo  = (const int*)d_in[6];
    const int*   gnum   = (const int*)d_in[7];
    const int*   pairs  = (const int*)d_in[8];
    const int*   pdist  = (const int*)d_in[9];
    const float* wt     = (const float*)d_in[10];
    const float* tt     = (const float*)d_in[11];
    const float* it     = (const float*)d_in[12];
    const float* Wihf   = (const float*)d_in[13];
    const float* Whhf   = (const float*)d_in[14];
    const float* bf     = (const float*)d_in[15];
    const float* Wihb   = (const float*)d_in[16];
    const float* Whhb   = (const float*)d_in[17];
    const float* bb     = (const float*)d_in[18];
    const float* W1     = (const float*)d_in[19];
    const float* b1     = (const float*)d_in[20];
    const float* W2     = (const float*)d_in[21];
    const float* b2     = (const float*)d_in[22];
    const float* dis    = (const float*)d_in[23];
    const float* pW1    = (const float*)d_in[24];
    const float* pb1    = (const float*)d_in[25];
    const float* pW2    = (const float*)d_in[26];
    const float* pb2    = (const float*)d_in[27];
    float* out = (float*)d_out;

    char* wsb = (char*)d_ws;
    size_t off = 0;
    auto carve = [&](size_t nf) {
        float* p = (float*)(wsb + off);
        off += ((nf * 4 + 255) / 256) * 256;
        return p;
    };
    float* WfT  = carve((size_t)IN_ * G4_);
    float* WbT  = carve((size_t)IN_ * G4_);
    float* xf   = carve((size_t)S_ * B_ * G4_);
    float* xb   = carve((size_t)S_ * B_ * G4_);
    float* hfb  = carve((size_t)S_ * B_ * H_);
    float* hbb  = carve((size_t)S_ * B_ * H_);
    float* feat = carve((size_t)B_ * N_ * BANK_);
    float* An   = carve((size_t)B_ * N_ * N_);
    float* M    = carve((size_t)B_ * N_ * GD_);
    float* eb   = carve((size_t)B_ * E_ * BANK_);
    float* U1   = carve((size_t)B_ * E_ * UC_);
    float* U2   = carve((size_t)B_ * E_ * UC_);
    float* Dm   = carve((size_t)20 * UC_);
    (void)ws_size; (void)in_sizes; (void)n_in; (void)out_size;

    misc_prep<<<1424, 256, 0, stream>>>(Wihf, Wihb, WfT, WbT, adj, gnum, An, dis, pW1, pb1, Dm);
    embed_xpre<<<512, 512, 0, stream>>>(words, etype, eidm, wt, tt, it, WfT, WbT, bf, bb, xf, xb);
    lstm_kernel<<<32, 512, 0, stream>>>(xf, xb, Whhf, Whhb, hfb, hbb);
    span_mean<<<B_ * N_, 256, 0, stream>>>(hfb, hbb, ginfo, gnum, srclen, feat);
    gcn_agg<<<dim3(16, 32), 256, 0, stream>>>(An, feat, 0, M);
    gcn_dense<<<dim3(16, 32), 256, 0, stream>>>(M, W1, b1, feat, 1);
    gcn_agg<<<dim3(16, 32), 256, 0, stream>>>(An, feat, 1, M);
    gcn_dense<<<dim3(16, 32), 256, 0, stream>>>(M, W2, b2, feat, 2);
    ebank_kernel<<<B_ * E_, 256, 0, stream>>>(ginfo, gnum, feat, eb);
    ugemm<<<dim3(12, 48), 256, 0, stream>>>(eb, pW1, U1, U2);
    scores_kernel<<<256, 256, 0, stream>>>(U1, U2, Dm, pW2, pb2, pairs, pdist, out);
}

// Round 9
// 1071.402 us; speedup vs baseline: 1.3547x; 1.0273x over previous
//
#include <hip/hip_runtime.h>
#include <math.h>

// ---------------- dims ----------------
static constexpr int B_ = 16, S_ = 512, H_ = 128, G4_ = 512, IN_ = 140;
static constexpr int GD_ = 256, N_ = 128, E_ = 48, P_ = 512, R_ = 97;
static constexpr int BANK_ = 768, UC_ = 1536; // U cols

__device__ __forceinline__ float fsig(float x) {
    return __builtin_amdgcn_rcpf(1.0f + __expf(-x));
}
__device__ __forceinline__ float ftanh(float x) {
    float e = __expf(2.0f * fminf(x, 15.0f));
    return (e - 1.0f) * __builtin_amdgcn_rcpf(e + 1.0f);
}

// ---------------- K0: fused prep: transpose Wih | Anorm | Dm ----------------
// blocks [0,280): transpose; [280,1304): Anorm (2 rows each); [1304,1424): Dm
__global__ __launch_bounds__(256) void misc_prep(
    const float* __restrict__ Wf, const float* __restrict__ Wb,
    float* __restrict__ WfT, float* __restrict__ WbT,
    const int* __restrict__ adj, const int* __restrict__ gnum, float* __restrict__ An,
    const float* __restrict__ dis, const float* __restrict__ pW1,
    const float* __restrict__ pb1, float* __restrict__ Dm) {
    int bid = blockIdx.x, tid = threadIdx.x;
    if (bid < 280) {
        int i = bid * 256 + tid;
        if (i < G4_ * IN_) {
            int jj = i / IN_, k = i - jj * IN_;
            WfT[k * G4_ + jj] = Wf[i];
            WbT[k * G4_ + jj] = Wb[i];
        }
    } else if (bid < 1304) {
        int rr = (bid - 280) * 2 + (tid >> 7);
        int b = rr >> 7, m = rr & 127, n = tid & 127;
        int num = gnum[b];
        float a = (adj[(b * N_ + m) * N_ + n] > 0 && m < num && n < num) ? 1.0f : 0.0f;
        float r = a;
#pragma unroll
        for (int off = 32; off > 0; off >>= 1) r += __shfl_down(r, off, 64);
        __shared__ float ws4[4];
        if ((tid & 63) == 0) ws4[tid >> 6] = r;
        __syncthreads();
        int w0 = (tid >> 7) * 2;
        float total = ws4[w0] + ws4[w0 + 1];
        An[(b * N_ + m) * N_ + n] = a / fmaxf(total, 1.0f);
    } else {
        int e = bid - 1304;
        int d = e / 6, cch = e - d * 6;
        int ci = cch * 256 + tid;
        float acc = pb1[ci];
#pragma unroll 4
        for (int q = 0; q < 20; ++q) acc += dis[d * 20 + q] * pW1[(2 * BANK_ + q) * UC_ + ci];
        Dm[d * UC_ + ci] = acc;
    }
}

// ---------------- K2: embedding + x @ Wih^T + b  (both dirs) ----------------
// grid 512 blocks x 512 threads; 16 rows per block; row = t*16+b
// xl is k-major [140][20] (pad 20 keeps float4 rows 16B-aligned, spreads banks)
__global__ __launch_bounds__(512) void embed_xpre(
    const int* __restrict__ words, const int* __restrict__ etype, const int* __restrict__ eidm,
    const float* __restrict__ wt, const float* __restrict__ tt, const float* __restrict__ it,
    const float* __restrict__ WfT, const float* __restrict__ WbT,
    const float* __restrict__ bf, const float* __restrict__ bb,
    float* __restrict__ xf, float* __restrict__ xb) {
    __shared__ float xl[IN_][20];
    int tid = threadIdx.x;
    int r0 = blockIdx.x * 16;
    for (int e = tid; e < 16 * IN_; e += 512) {
        int r = e / IN_, k = e - r * IN_;
        int rid = r0 + r, s = rid >> 4, b = rid & 15;
        float v;
        if (k < 100)      v = wt[words[b * S_ + s] * 100 + k];
        else if (k < 120) v = tt[etype[b * S_ + s] * 20 + (k - 100)];
        else              v = it[eidm[b * S_ + s] * 20 + (k - 120)];
        xl[k][r] = v;
    }
    __syncthreads();
    int j = tid;
    float accf[16], accb[16];
    float bfv = bf[j], bbv = bb[j];
#pragma unroll
    for (int r = 0; r < 16; ++r) { accf[r] = bfv; accb[r] = bbv; }
#pragma unroll 2
    for (int k = 0; k < IN_; ++k) {
        float wf = WfT[k * G4_ + j], wb = WbT[k * G4_ + j];
        float4 x0 = *reinterpret_cast<const float4*>(&xl[k][0]);
        float4 x1 = *reinterpret_cast<const float4*>(&xl[k][4]);
        float4 x2 = *reinterpret_cast<const float4*>(&xl[k][8]);
        float4 x3 = *reinterpret_cast<const float4*>(&xl[k][12]);
        float xr[16] = {x0.x, x0.y, x0.z, x0.w, x1.x, x1.y, x1.z, x1.w,
                        x2.x, x2.y, x2.z, x2.w, x3.x, x3.y, x3.z, x3.w};
#pragma unroll
        for (int r = 0; r < 16; ++r) {
            accf[r] += xr[r] * wf;
            accb[r] += xr[r] * wb;
        }
    }
#pragma unroll
    for (int r = 0; r < 16; ++r) {
        int rid = r0 + r;
        xf[rid * G4_ + j] = accf[r];
        xb[rid * G4_ + j] = accb[r];
    }
}

// ---------------- K3: BiLSTM, one chain per block ----------------
// grid 32 (dir*16+b), 512 threads = 8 waves x (16 units x 4 K-slices).
// Weights are loaded once and passed through an opaque asm barrier: the
// compiler cannot rematerialize them from memory, so they stay in VGPRs.
__global__ __launch_bounds__(512, 2) void lstm_kernel(
    const float* __restrict__ xf, const float* __restrict__ xb,
    const float* __restrict__ Whf, const float* __restrict__ Whb,
    float* __restrict__ hfo, float* __restrict__ hbo) {
    int bid = blockIdx.x;
    int dir = bid >> 4, b = bid & 15;
    const float* xpre = dir ? xb : xf;
    const float* Whh  = dir ? Whb : Whf;
    float* outp       = dir ? hbo : hfo;
    int tid  = threadIdx.x;
    int wave = tid >> 6;
    int lane = tid & 63;
    int j4   = lane & 15;
    int ks   = lane >> 4;          // 0..3
    int j    = wave * 16 + j4;     // hidden unit 0..127

    // per-thread weights: 4 gates x 32 K-slice = 128 VGPRs, static indexing
    float4 w4[4][8];
#pragma unroll
    for (int g = 0; g < 4; ++g)
#pragma unroll
        for (int q = 0; q < 8; ++q)
            w4[g][q] = *reinterpret_cast<const float4*>(
                &Whh[(j + 128 * g) * 128 + 32 * ks + 4 * q]);
    // Opaque pin: forbids re-loading these values inside the loop.
#pragma unroll
    for (int g = 0; g < 4; ++g)
#pragma unroll
        for (int q = 0; q < 8; ++q)
            asm volatile("" : "+v"(w4[g][q].x), "+v"(w4[g][q].y),
                              "+v"(w4[g][q].z), "+v"(w4[g][q].w));

    // h double-buffered; slice ks stored at row ks (stride 36 floats -> the
    // 4 slices start at banks 0,4,8,12: conflict-free b128 reads)
    __shared__ float hsh[2][4 * 36];
    if (tid < 128) {
        hsh[0][(tid >> 5) * 36 + (tid & 31)] = 0.0f;
        hsh[1][(tid >> 5) * 36 + (tid & 31)] = 0.0f;
    }
    float c = 0.0f;

    int t0 = dir ? (S_ - 1) : 0;
    const float* xr0 = &xpre[(t0 * B_ + b) * G4_];
    float xi = xr0[j], xfv = xr0[j + 128], xg = xr0[j + 256], xo = xr0[j + 384];
    __syncthreads();

    for (int t = 0; t < S_; ++t) {
        int tcur = dir ? (S_ - 1 - t) : t;
        float cxi = xi, cxf = xfv, cxg = xg, cxo = xo;
        if (t < S_ - 1) {
            int tn = dir ? (S_ - 2 - t) : (t + 1);
            const float* xr = &xpre[(tn * B_ + b) * G4_];
            xi = xr[j]; xfv = xr[j + 128]; xg = xr[j + 256]; xo = xr[j + 384];
        }
        const float* hrow = &hsh[t & 1][ks * 36];
        float ai = 0.f, af = 0.f, ag = 0.f, ao = 0.f;
#pragma unroll
        for (int q = 0; q < 8; ++q) {
            float4 hv = *reinterpret_cast<const float4*>(&hrow[4 * q]);
            ai += w4[0][q].x * hv.x + w4[0][q].y * hv.y + w4[0][q].z * hv.z + w4[0][q].w * hv.w;
            af += w4[1][q].x * hv.x + w4[1][q].y * hv.y + w4[1][q].z * hv.z + w4[1][q].w * hv.w;
            ag += w4[2][q].x * hv.x + w4[2][q].y * hv.y + w4[2][q].z * hv.z + w4[2][q].w * hv.w;
            ao += w4[3][q].x * hv.x + w4[3][q].y * hv.y + w4[3][q].z * hv.z + w4[3][q].w * hv.w;
        }
        // reduce across ks (lane bits 4,5)
        ai += __shfl_xor(ai, 16); ai += __shfl_xor(ai, 32);
        af += __shfl_xor(af, 16); af += __shfl_xor(af, 32);
        ag += __shfl_xor(ag, 16); ag += __shfl_xor(ag, 32);
        ao += __shfl_xor(ao, 16); ao += __shfl_xor(ao, 32);
        ai += cxi; af += cxf; ag += cxg; ao += cxo;
        float si = fsig(ai), sf = fsig(af), so = fsig(ao);
        c = sf * c + si * ftanh(ag);
        float h = so * ftanh(c);
        if (ks == 0) {
            hsh[1 - (t & 1)][(j >> 5) * 36 + (j & 31)] = h;
            outp[(tcur * B_ + b) * H_ + j] = h;
        }
        __syncthreads();
    }
}

// ---------------- K4: span means -> feat slice 0 ----------------
// grid 2048 (b*128+n), 256 threads (channel)
__global__ void span_mean(const float* __restrict__ hf, const float* __restrict__ hb,
                          const int* __restrict__ ginfo, const int* __restrict__ gnum,
                          const int* __restrict__ srclen, float* __restrict__ feat) {
    int bidx = blockIdx.x, b = bidx >> 7, n = bidx & 127;
    int c = threadIdx.x;
    int st = ginfo[(b * N_ + n) * 4 + 0];
    int en = ginfo[(b * N_ + n) * 4 + 1];
    int num = gnum[b], lb = srclen[b];
    float acc = 0.0f;
    for (int s = st; s < en; ++s) {
        if (s < lb) {
            acc += (c < H_) ? hf[(s * B_ + b) * H_ + c]
                            : hb[(s * B_ + b) * H_ + (c - H_)];
        }
    }
    int len = en - st; if (len < 1) len = 1;
    float v = acc / (float)len;
    if (n >= num) v = 0.0f;
    feat[(b * N_ + n) * BANK_ + c] = v;
}

// ---------------- K6: M = Anorm @ X(slice) ----------------
// grid (16, 32): 4 m-rows per block; 256 threads (channel)
__global__ void gcn_agg(const float* __restrict__ An, const float* __restrict__ feat,
                        int slice, float* __restrict__ M) {
    int b = blockIdx.x, m0 = blockIdx.y * 4;
    int tid = threadIdx.x;
    __shared__ float ar[4][N_];
    for (int e = tid; e < 4 * N_; e += 256)
        ar[e >> 7][e & 127] = An[(b * N_ + m0 + (e >> 7)) * N_ + (e & 127)];
    __syncthreads();
    float acc[4] = {0.f, 0.f, 0.f, 0.f};
    int c = tid;
    const float* fbase = &feat[(size_t)b * N_ * BANK_ + slice * GD_ + c];
    for (int n = 0; n < N_; n += 4) {
        float x0 = fbase[(size_t)(n + 0) * BANK_];
        float x1 = fbase[(size_t)(n + 1) * BANK_];
        float x2 = fbase[(size_t)(n + 2) * BANK_];
        float x3 = fbase[(size_t)(n + 3) * BANK_];
#pragma unroll
        for (int r = 0; r < 4; ++r) {
            float4 a = *reinterpret_cast<const float4*>(&ar[r][n]);
            acc[r] += a.x * x0 + a.y * x1 + a.z * x2 + a.w * x3;
        }
    }
#pragma unroll
    for (int r = 0; r < 4; ++r) M[(b * N_ + m0 + r) * GD_ + c] = acc[r];
}

// ---------------- K7: h = relu(M @ W + bias) -> feat slice ----------------
__global__ void gcn_dense(const float* __restrict__ M, const float* __restrict__ W,
                          const float* __restrict__ bias, float* __restrict__ feat,
                          int outslice) {
    int b = blockIdx.x, m0 = blockIdx.y * 4;
    int tid = threadIdx.x;
    __shared__ float mr[4][GD_];
    for (int e = tid; e < 4 * GD_; e += 256)
        mr[e >> 8][e & 255] = M[(b * N_ + m0 + (e >> 8)) * GD_ + (e & 255)];
    __syncthreads();
    int c = tid;
    float bv = bias[c];
    float acc[4] = {bv, bv, bv, bv};
    for (int d = 0; d < GD_; d += 4) {
        float w0 = W[(d + 0) * GD_ + c];
        float w1 = W[(d + 1) * GD_ + c];
        float w2 = W[(d + 2) * GD_ + c];
        float w3 = W[(d + 3) * GD_ + c];
#pragma unroll
        for (int r = 0; r < 4; ++r) {
            float4 m = *reinterpret_cast<const float4*>(&mr[r][d]);
            acc[r] += m.x * w0 + m.y * w1 + m.z * w2 + m.w * w3;
        }
    }
#pragma unroll
    for (int r = 0; r < 4; ++r)
        feat[(b * N_ + m0 + r) * BANK_ + outslice * GD_ + c] = fmaxf(acc[r], 0.0f);
}

// ---------------- K8: entity bank ----------------
// grid 768 (b*48+e), 256 threads
__global__ void ebank_kernel(const int* __restrict__ ginfo, const int* __restrict__ gnum,
                             const float* __restrict__ feat, float* __restrict__ eb) {
    int bidx = blockIdx.x, b = bidx / E_, e = bidx % E_;
    int tid = threadIdx.x;
    __shared__ int fl[N_];
    int num = gnum[b];
    if (tid < N_) {
        int n = tid;
        int id = ginfo[(b * N_ + n) * 4 + 2];
        int ty = ginfo[(b * N_ + n) * 4 + 3];
        fl[n] = (ty == 2 && n < num) ? id : -1;
    }
    __syncthreads();
    float a0 = 0.f, a1 = 0.f, a2 = 0.f; int cnt = 0;
    for (int n = 0; n < N_; ++n) {
        if (fl[n] == e) {
            ++cnt;
            const float* fp = &feat[(b * N_ + n) * BANK_];
            a0 += fp[tid]; a1 += fp[256 + tid]; a2 += fp[512 + tid];
        }
    }
    float inv = 1.0f / (float)(cnt > 0 ? cnt : 1);
    float* o = &eb[(b * E_ + e) * BANK_];
    o[tid] = a0 * inv; o[256 + tid] = a1 * inv; o[512 + tid] = a2 * inv;
}

// ---------------- K10: U1/U2 = entity_bank @ pW1 halves ----------------
// C[768 x 3072], K=768. grid (12, 48), 256 thr, 64x64 tile, 4x4 per thread.
__global__ __launch_bounds__(256) void ugemm(const float* __restrict__ eb,
                                             const float* __restrict__ pW1,
                                             float* __restrict__ U1, float* __restrict__ U2) {
    int rt = blockIdx.x, ct = blockIdx.y;
    int tid = threadIdx.x;
    int half = (ct >= 24) ? 1 : 0;
    int jbase = (ct - half * 24) * 64;
    int wrow = half * BANK_;
    __shared__ float At[32][68];
    __shared__ float Bt[32][68];
    int rg = tid >> 4, cg = tid & 15;
    int r0 = rt * 64;
    float acc[4][4] = {};
    for (int kc = 0; kc < BANK_; kc += 32) {
#pragma unroll
        for (int i = 0; i < 8; ++i) {
            int e = tid + i * 256, r = e >> 5, k = e & 31;
            At[k][r] = eb[(r0 + r) * BANK_ + kc + k];
        }
#pragma unroll
        for (int i = 0; i < 8; ++i) {
            int e = tid + i * 256, k = e >> 6, cc = e & 63;
            Bt[k][cc] = pW1[(wrow + kc + k) * UC_ + jbase + cc];
        }
        __syncthreads();
#pragma unroll
        for (int k = 0; k < 32; ++k) {
            float4 a  = *reinterpret_cast<const float4*>(&At[k][rg * 4]);
            float4 bv = *reinterpret_cast<const float4*>(&Bt[k][cg * 4]);
            float ax[4] = {a.x, a.y, a.z, a.w};
            float bx[4] = {bv.x, bv.y, bv.z, bv.w};
#pragma unroll
            for (int r = 0; r < 4; ++r)
#pragma unroll
                for (int q = 0; q < 4; ++q) acc[r][q] += ax[r] * bx[q];
        }
        __syncthreads();
    }
    float* U = half ? U2 : U1;
#pragma unroll
    for (int r = 0; r < 4; ++r)
#pragma unroll
        for (int q = 0; q < 4; ++q)
            U[(r0 + rg * 4 + r) * UC_ + jbase + cg * 4 + q] = acc[r][q];
}

// ---------------- K11: scores = tanh(U1[h]+U2[t]+D[d]) @ pW2 + pb2 ----------------
// grid 256 (32 rows each), 256 threads; KC=96; T^T[k][r] stride 36, W[k][c] stride 100.
__global__ __launch_bounds__(256) void scores_kernel(
    const float* __restrict__ U1, const float* __restrict__ U2, const float* __restrict__ Dm,
    const float* __restrict__ pW2, const float* __restrict__ pb2,
    const int* __restrict__ pairs, const int* __restrict__ pdist, float* __restrict__ out) {
    int blk = blockIdx.x;
    int row0 = blk * 32;
    int b = row0 >> 9, p0 = row0 & 511;
    int tid = threadIdx.x;
    __shared__ float Tt[96 * 36];
    __shared__ float Wl[96 * 100];
    __shared__ int hidx[32], tidx[32], didx[32];
    if (tid < 32) {
        int p = p0 + tid;
        hidx[tid] = pairs[(b * P_ + p) * 2 + 0];
        tidx[tid] = pairs[(b * P_ + p) * 2 + 1];
        didx[tid] = pdist[b * P_ + p];
    }
    __syncthreads();
    int rg = tid / 25, cg = tid % 25;   // 8 x 25 = 200 active
    bool act = tid < 200;
    float acc[4][4] = {};
    for (int kc = 0; kc < UC_; kc += 96) {
        // stage pW2 chunk
        for (int k2 = tid; k2 < 96 * 128; k2 += 256) {
            int k = k2 >> 7, cc = k2 & 127;
            if (cc < 100) Wl[k * 100 + cc] = (cc < R_) ? pW2[(kc + k) * R_ + cc] : 0.0f;
        }
        // stage tanh(U1+U2+D) transposed
        for (int e = tid; e < 32 * 96; e += 256) {
            int r = e / 96, k = e % 96, gk = kc + k;
            float v = U1[(b * E_ + hidx[r]) * UC_ + gk]
                    + U2[(b * E_ + tidx[r]) * UC_ + gk]
                    + Dm[didx[r] * UC_ + gk];
            Tt[k * 36 + r] = ftanh(v);
        }
        __syncthreads();
        if (act) {
#pragma unroll 4
            for (int k = 0; k < 96; ++k) {
                float4 a  = *reinterpret_cast<const float4*>(&Tt[k * 36 + rg * 4]);
                float4 wv = *reinterpret_cast<const float4*>(&Wl[k * 100 + cg * 4]);
                float ax[4] = {a.x, a.y, a.z, a.w};
                float wx[4] = {wv.x, wv.y, wv.z, wv.w};
#pragma unroll
                for (int r = 0; r < 4; ++r)
#pragma unroll
                    for (int q = 0; q < 4; ++q) acc[r][q] += ax[r] * wx[q];
            }
        }
        __syncthreads();
    }
    if (act) {
#pragma unroll
        for (int r = 0; r < 4; ++r) {
            int prow = row0 + rg * 4 + r;
#pragma unroll
            for (int q = 0; q < 4; ++q) {
                int col = cg * 4 + q;
                if (col < R_) out[prow * R_ + col] = acc[r][q] + pb2[col];
            }
        }
    }
}

// ---------------- launcher ----------------
extern "C" void kernel_launch(void* const* d_in, const int* in_sizes, int n_in,
                              void* d_out, int out_size, void* d_ws, size_t ws_size,
                              hipStream_t stream) {
    const int*   words  = (const int*)d_in[0];
    const int*   etype  = (const int*)d_in[2];
    const int*   eidm   = (const int*)d_in[3];
    const int*   srclen = (const int*)d_in[4];
    const int*   adj    = (const int*)d_in[5];
    const int*   ginfo  = (const int*)d_in[6];
    const int*   gnum   = (const int*)d_in[7];
    const int*   pairs  = (const int*)d_in[8];
    const int*   pdist  = (const int*)d_in[9];
    const float* wt     = (const float*)d_in[10];
    const float* tt     = (const float*)d_in[11];
    const float* it     = (const float*)d_in[12];
    const float* Wihf   = (const float*)d_in[13];
    const float* Whhf   = (const float*)d_in[14];
    const float* bf     = (const float*)d_in[15];
    const float* Wihb   = (const float*)d_in[16];
    const float* Whhb   = (const float*)d_in[17];
    const float* bb     = (const float*)d_in[18];
    const float* W1     = (const float*)d_in[19];
    const float* b1     = (const float*)d_in[20];
    const float* W2     = (const float*)d_in[21];
    const float* b2     = (const float*)d_in[22];
    const float* dis    = (const float*)d_in[23];
    const float* pW1    = (const float*)d_in[24];
    const float* pb1    = (const float*)d_in[25];
    const float* pW2    = (const float*)d_in[26];
    const float* pb2    = (const float*)d_in[27];
    float* out = (float*)d_out;

    char* wsb = (char*)d_ws;
    size_t off = 0;
    auto carve = [&](size_t nf) {
        float* p = (float*)(wsb + off);
        off += ((nf * 4 + 255) / 256) * 256;
        return p;
    };
    float* WfT  = carve((size_t)IN_ * G4_);
    float* WbT  = carve((size_t)IN_ * G4_);
    float* xf   = carve((size_t)S_ * B_ * G4_);
    float* xb   = carve((size_t)S_ * B_ * G4_);
    float* hfb  = carve((size_t)S_ * B_ * H_);
    float* hbb  = carve((size_t)S_ * B_ * H_);
    float* feat = carve((size_t)B_ * N_ * BANK_);
    float* An   = carve((size_t)B_ * N_ * N_);
    float* M    = carve((size_t)B_ * N_ * GD_);
    float* eb   = carve((size_t)B_ * E_ * BANK_);
    float* U1   = carve((size_t)B_ * E_ * UC_);
    float* U2   = carve((size_t)B_ * E_ * UC_);
    float* Dm   = carve((size_t)20 * UC_);
    (void)ws_size; (void)in_sizes; (void)n_in; (void)out_size;

    misc_prep<<<1424, 256, 0, stream>>>(Wihf, Wihb, WfT, WbT, adj, gnum, An, dis, pW1, pb1, Dm);
    embed_xpre<<<512, 512, 0, stream>>>(words, etype, eidm, wt, tt, it, WfT, WbT, bf, bb, xf, xb);
    lstm_kernel<<<32, 512, 0, stream>>>(xf, xb, Whhf, Whhb, hfb, hbb);
    span_mean<<<B_ * N_, 256, 0, stream>>>(hfb, hbb, ginfo, gnum, srclen, feat);
    gcn_agg<<<dim3(16, 32), 256, 0, stream>>>(An, feat, 0, M);
    gcn_dense<<<dim3(16, 32), 256, 0, stream>>>(M, W1, b1, feat, 1);
    gcn_agg<<<dim3(16, 32), 256, 0, stream>>>(An, feat, 1, M);
    gcn_dense<<<dim3(16, 32), 256, 0, stream>>>(M, W2, b2, feat, 2);
    ebank_kernel<<<B_ * E_, 256, 0, stream>>>(ginfo, gnum, feat, eb);
    ugemm<<<dim3(12, 48), 256, 0, stream>>>(eb, pW1, U1, U2);
    scores_kernel<<<256, 256, 0, stream>>>(U1, U2, Dm, pW2, pb2, pairs, pdist, out);
}